// Round 12
// baseline (340.245 us; speedup 1.0000x reference)
//
#include <hip/hip_runtime.h>
#include <hip/hip_bf16.h>
#include <stdint.h>

typedef __attribute__((ext_vector_type(4))) float f32x4;

#define M_ROWS 8192
#define K_DIM  4096
#define N_COLS 4096
#define NT     (K_DIM / 64)   // 64 K-tiles (64 fp8 bytes of K each)
#define NWG    ((M_ROWS / 256) * (N_COLS / 256))  // 512
#define WL_CAP (1 << 20)
#define XSHIFT 6
#define WSHIFT 8
#define SUMSHIFT (XSHIFT + WSHIFT)  // 14: S_mfma = S_true * 2^14

// sqrt(2) in fp64: 0x3FF6A09E667F3BCD (slightly ABOVE true sqrt2).
#define SQRT2_MANT 0x6A09E667F3BCDLL
// flag margin: ~2^-11 relative; hard MFMA accum bound 2^-12 + fp8-flush ~2^-24
#define FLAG_MARGIN 3110000000000LL

__device__ __forceinline__ int rlog2_mask(double a) {
    if (!(a > 1e-38)) return -128;
    long long b = __double_as_longlong(a);
    int E = (int)(b >> 52) - 1023;
    long long m = b & 0xFFFFFFFFFFFFFLL;
    int e = E + (int)(m >= SQRT2_MANT);
    return e < -128 ? -128 : (e > 127 ? 127 : e);
}

__device__ __forceinline__ double pow2d(int e) {
    return __longlong_as_double((long long)(e + 1023) << 52);
}

__device__ __forceinline__ float finalize_out(int em, int ebj) {
    double s = pow2d(em) + pow2d(ebj);
    return (float)pow2d(rlog2_mask(s));
}

// exact e5m2 encoding of 2^d (d<=15; subnormals to 2^-16; else 0)
__device__ __forceinline__ unsigned char enc_e5m2(int d) {
    if (d > 15) d = 15;              // unreachable for this data; NaN/inf guard
    if (d >= -14) return (unsigned char)((d + 15) << 2);
    if (d == -15) return 0x02;
    if (d == -16) return 0x01;
    return 0;
}

// ---------------- quantization: fp32 -> {e5m2 scaled byte, int8 exponent} ----------------
__global__ void quant8_kernel(const float* __restrict__ in, unsigned char* __restrict__ q8,
                              char* __restrict__ e8, int n4, int shift) {
    int idx = blockIdx.x * blockDim.x + threadIdx.x;
    int stride = gridDim.x * blockDim.x;
    for (int i = idx; i < n4; i += stride) {
        float4 v = ((const float4*)in)[i];
        int ex = rlog2_mask(fabs((double)v.x));
        int ey = rlog2_mask(fabs((double)v.y));
        int ez = rlog2_mask(fabs((double)v.z));
        int ew = rlog2_mask(fabs((double)v.w));
        uchar4 q; char4 e;
        q.x = enc_e5m2(ex + shift); e.x = (char)ex;
        q.y = enc_e5m2(ey + shift); e.y = (char)ey;
        q.z = enc_e5m2(ez + shift); e.z = (char)ez;
        q.w = enc_e5m2(ew + shift); e.w = (char)ew;
        ((uchar4*)q8)[i] = q;
        ((char4*)e8)[i] = e;
    }
}

__global__ void quant_bias_kernel(const float* __restrict__ b, int* __restrict__ eb, int n) {
    int i = blockIdx.x * blockDim.x + threadIdx.x;
    if (i < n) eb[i] = rlog2_mask(fabs((double)b[i]));
}

// ---------------- 256x256 GEMM (non-scaled bf8 MFMA 16x16x32, b128 operand reads) ----------------
__device__ __forceinline__ void g2l(const unsigned char* g, unsigned char* l) {
    __builtin_amdgcn_global_load_lds(
        (const __attribute__((address_space(1))) unsigned int*)g,
        (__attribute__((address_space(3))) unsigned int*)l, 16, 0, 0);
}

#define MFMA8(a, b, c) __builtin_amdgcn_mfma_f32_16x16x32_bf8_bf8((long)(a), (long)(b), (c), 0, 0, 0)

__global__ __launch_bounds__(512, 2) void gemm_kernel(
    const unsigned char* __restrict__ xq8, const unsigned char* __restrict__ wq8,
    const int* __restrict__ eb, float* __restrict__ out,
    int* __restrict__ wl_count, int* __restrict__ wl)
{
    // Per 32KB buffer: A [0,16384) = [256 rows][64B]; B [16384,32768) = [256 rows][64B].
    // Block swizzle (16B granule): LDS[row][blk] = G[row][blk ^ sigma(row)],
    // sigma(r) = (r ^ (r>>2)) & 3. Lane-group lhi owns contiguous k-block lhi*16..+15
    // (a k-permutation applied identically to A and B -> dot product invariant),
    // fetched with ONE ds_read_b128: lo u64 -> MFMA#1 operand, hi u64 -> MFMA#2.
    __shared__ unsigned char lds8[2][32768];

    const int tid = threadIdx.x;
    const int lane = tid & 63, w = tid >> 6;
    const int wm = w >> 2, wn = w & 3;
    const int l15 = lane & 15, lhi = lane >> 4;

    // 2D XCD tiling (proven: FETCH 541->197 MB on bf16)
    const int x = blockIdx.x & 7;
    const int j = blockIdx.x >> 3;
    const int bm = (x & 3) * 8 + (j & 7);
    const int bn = (x >> 2) * 8 + ((j >> 3) & 3) + (j >> 5) * 4;
    const int brow = bm * 256, bcol = bn * 256;

    // ---- staging source (pre-swizzled global, linear LDS dest) ----
    // thread t: row rs = t>>2 (128 rows/call), LDS block = t&3; src block = (t&3)^sigma(rs)
    const int rs = tid >> 2;
    const int sig_rs = (rs ^ (rs >> 2)) & 3;
    const int scol = (((tid & 3) ^ sig_rs) << 4);

    const unsigned char* aH0 = xq8 + (size_t)(brow +   0 + rs) * K_DIM + scol;
    const unsigned char* aH1 = xq8 + (size_t)(brow + 128 + rs) * K_DIM + scol;
    const unsigned char* bH0 = wq8 + (size_t)(bcol +   0 + rs) * K_DIM + scol;
    const unsigned char* bH1 = wq8 + (size_t)(bcol + 128 + rs) * K_DIM + scol;

    const int wofs = w * 1024;

#define STAGE_A(b, OFFE) do { \
        g2l(aH0 + (OFFE), &lds8[b][0]     + wofs); \
        g2l(aH1 + (OFFE), &lds8[b][8192]  + wofs); \
    } while (0)
#define STAGE_B(b, OFFE) do { \
        g2l(bH0 + (OFFE), &lds8[b][16384] + wofs); \
        g2l(bH1 + (OFFE), &lds8[b][24576] + wofs); \
    } while (0)

    // ---- fragment read bases: row = l15 (+16 per m/n tile), k-block = lhi ----
    const int sig_l = (l15 ^ (l15 >> 2)) & 3;
    const int fsw = ((lhi ^ sig_l) << 4);           // swizzled 16B block within row
    const int aro = (wm * 128 + l15) * 64 + fsw;
    const int bro = 16384 + (wn * 64 + l15) * 64 + fsw;

    const char* pA_0 = (const char*)&lds8[0][0] + aro;
    const char* pA_1 = (const char*)&lds8[1][0] + aro;
    const char* pB_0 = (const char*)&lds8[0][0] + bro;
    const char* pB_1 = (const char*)&lds8[1][0] + bro;

    f32x4 acc[8][4];
#pragma unroll
    for (int m = 0; m < 8; ++m)
#pragma unroll
        for (int n = 0; n < 4; ++n) acc[m][n] = (f32x4){0.f, 0.f, 0.f, 0.f};

    ulonglong2 aF[4], bF[4];

#define LD128(p, off) (*(const ulonglong2*)((const char*)(p) + (off)))
#define DS_A4(P, mb) do { \
        aF[0] = LD128(P, ((mb) + 0) * 1024); \
        aF[1] = LD128(P, ((mb) + 1) * 1024); \
        aF[2] = LD128(P, ((mb) + 2) * 1024); \
        aF[3] = LD128(P, ((mb) + 3) * 1024); \
    } while (0)
#define DS_B4(P) do { \
        bF[0] = LD128(P, 0 * 1024); \
        bF[1] = LD128(P, 1 * 1024); \
        bF[2] = LD128(P, 2 * 1024); \
        bF[3] = LD128(P, 3 * 1024); \
    } while (0)
#define MFMA_H(mb) do { \
        _Pragma("unroll") \
        for (int m_ = 0; m_ < 4; ++m_) \
        _Pragma("unroll") \
        for (int n_ = 0; n_ < 4; ++n_) { \
            acc[(mb) + m_][n_] = MFMA8(aF[m_].x, bF[n_].x, acc[(mb) + m_][n_]); \
            acc[(mb) + m_][n_] = MFMA8(aF[m_].y, bF[n_].y, acc[(mb) + m_][n_]); \
        } \
    } while (0)

#define BAR()  __builtin_amdgcn_s_barrier()
#define PRIO1() __builtin_amdgcn_s_setprio(1)
#define PRIO0() __builtin_amdgcn_s_setprio(0)

    // ---- prologue: buf0 <- tile0 (A,B), buf1 <- B(1); vmcnt(2) leaves buf1.B in flight ----
    STAGE_A(0, 0);
    STAGE_B(0, 0);
    STAGE_B(1, 64);
    asm volatile("s_waitcnt vmcnt(2)" ::: "memory");
    BAR();

    // ---- main loop: 2 K-tiles (T=2tt -> buf0, T+1 -> buf1), 4 phases ----
    for (int tt = 0; tt < NT / 2 - 1; ++tt) {
        // P1: stage buf1.A(T+1); read buf0 A(m0-3)+B; MFMA m0-3
        STAGE_A(1, 64);
        DS_A4(pA_0, 0);
        DS_B4(pB_0);
        PRIO1(); MFMA_H(0); PRIO0(); BAR();
        // P2: stage buf0.B(T+2); read buf0 A(m4-7); MFMA m4-7; vmcnt(2) -> buf1 complete
        STAGE_B(0, 128);
        DS_A4(pA_0, 4);
        PRIO1(); MFMA_H(4); PRIO0();
        asm volatile("s_waitcnt vmcnt(2)" ::: "memory");
        BAR();
        // P3: stage buf0.A(T+2); read buf1 A(m0-3)+B; MFMA m0-3
        STAGE_A(0, 128);
        DS_A4(pA_1, 0);
        DS_B4(pB_1);
        PRIO1(); MFMA_H(0); PRIO0(); BAR();
        // P4: stage buf1.B(T+3); read buf1 A(m4-7); MFMA m4-7; vmcnt(2) -> buf0 complete
        STAGE_B(1, 192);
        DS_A4(pA_1, 4);
        PRIO1(); MFMA_H(4); PRIO0();
        asm volatile("s_waitcnt vmcnt(2)" ::: "memory");
        BAR();

        aH0 += 128; aH1 += 128; bH0 += 128; bH1 += 128;
    }

    // ---- peeled final pair (tiles NT-2 -> buf0, NT-1 -> buf1) ----
    STAGE_A(1, 64);
    DS_A4(pA_0, 0);
    DS_B4(pB_0);
    PRIO1(); MFMA_H(0); PRIO0(); BAR();
    DS_A4(pA_0, 4);
    PRIO1(); MFMA_H(4); PRIO0();
    asm volatile("s_waitcnt vmcnt(0)" ::: "memory");
    BAR();
    DS_A4(pA_1, 0);
    DS_B4(pB_1);
    PRIO1(); MFMA_H(0); PRIO0(); BAR();
    DS_A4(pA_1, 4);
    PRIO1(); MFMA_H(4); PRIO0();

    // ---- epilogue: exponent decision (undo 2^14 scale) + flag + finalize ----
#pragma unroll
    for (int m = 0; m < 8; ++m) {
        int grow_base = brow + wm * 128 + m * 16 + lhi * 4;
#pragma unroll
        for (int n = 0; n < 4; ++n) {
            int gcol = bcol + wn * 64 + n * 16 + l15;
            int ebj = eb[gcol];
#pragma unroll
            for (int q = 0; q < 4; ++q) {
                float S = acc[m][n][q];
                int grow = grow_base + q;
                double v = (double)S;
                int em; bool flag;
                if (v > 1e-38) {
                    long long bb = __double_as_longlong(v);
                    long long mm = bb & 0xFFFFFFFFFFFFFLL;
                    long long d = mm - SQRT2_MANT;
                    flag = (d < 0 ? -d : d) < FLAG_MARGIN;
                    int e = ((int)(bb >> 52) - 1023) + (int)(mm >= SQRT2_MANT) - SUMSHIFT;
                    em = e < -128 ? -128 : (e > 127 ? 127 : e);
                } else { em = -128; flag = true; }
                out[(size_t)grow * N_COLS + gcol] = finalize_out(em, ebj);
                if (flag) {
                    int pos = atomicAdd(wl_count, 1);
                    if (pos < WL_CAP) wl[pos] = grow * N_COLS + gcol;
                }
            }
        }
    }
}

// ---------------- exact fixup for flagged outputs (int8 exponent arrays) ----------------
__global__ __launch_bounds__(256) void fixup_kernel(
    const char* __restrict__ xe, const char* __restrict__ we,
    const int* __restrict__ eb, float* __restrict__ out,
    const int* __restrict__ wl_count, const int* __restrict__ wl)
{
    const int nwaves = (gridDim.x * blockDim.x) >> 6;
    const int gw = (blockIdx.x * blockDim.x + threadIdx.x) >> 6;
    const int lane = threadIdx.x & 63;
    int count = *wl_count;
    if (count > WL_CAP) count = WL_CAP;
    for (int it = gw; it < count; it += nwaves) {
        int lin = wl[it];
        int i = lin >> 12;
        int j = lin & 4095;
        const char* xr = xe + (size_t)i * K_DIM;
        const char* wr = we + (size_t)j * K_DIM;
        unsigned long long accu = 0;
        for (int kbk = 0; kbk < K_DIM / 256; ++kbk) {
            int k0 = kbk * 256 + lane * 4;
            char4 xv = *(const char4*)(xr + k0);
            char4 wv = *(const char4*)(wr + k0);
            int p;
            p = (int)xv.x + (int)wv.x + 56; if ((unsigned)p <= 62u) accu += 1ULL << p;
            p = (int)xv.y + (int)wv.y + 56; if ((unsigned)p <= 62u) accu += 1ULL << p;
            p = (int)xv.z + (int)wv.z + 56; if ((unsigned)p <= 62u) accu += 1ULL << p;
            p = (int)xv.w + (int)wv.w + 56; if ((unsigned)p <= 62u) accu += 1ULL << p;
        }
#pragma unroll
        for (int off = 32; off; off >>= 1) accu += __shfl_down(accu, off, 64);
        if (lane == 0) {
            double S = (double)accu * 0x1p-56;
            int em = rlog2_mask(S);
            out[lin] = finalize_out(em, eb[j]);
        }
    }
}

extern "C" void kernel_launch(void* const* d_in, const int* in_sizes, int n_in,
                              void* d_out, int out_size, void* d_ws, size_t ws_size,
                              hipStream_t stream) {
    const float* x    = (const float*)d_in[0];
    const float* w    = (const float*)d_in[1];
    const float* bias = (const float*)d_in[2];
    float* out = (float*)d_out;
    char* ws = (char*)d_ws;

    const size_t MK = (size_t)M_ROWS * K_DIM;  // 33.55 MB
    const size_t NK = (size_t)N_COLS * K_DIM;  // 16.78 MB

    int* wl_count = (int*)ws;
    int* eb       = (int*)(ws + 256);
    unsigned char* xq8 = (unsigned char*)(ws + 32768);
    unsigned char* wq8 = (unsigned char*)(ws + 32768 + MK);
    char* xe = (char*)(ws + 32768 + MK + NK);
    char* we = (char*)(ws + 32768 + 2 * MK + NK);
    int* wl  = (int*)(ws + 32768 + 2 * MK + 2 * NK);

    hipMemsetAsync(wl_count, 0, 4, stream);
    quant8_kernel<<<2048, 256, 0, stream>>>(x, xq8, xe, (int)(MK / 4), XSHIFT);
    quant8_kernel<<<1024, 256, 0, stream>>>(w, wq8, we, (int)(NK / 4), WSHIFT);
    quant_bias_kernel<<<16, 256, 0, stream>>>(bias, eb, N_COLS);
    gemm_kernel<<<dim3(NWG), 512, 0, stream>>>(xq8, wq8, eb, out, wl_count, wl);
    fixup_kernel<<<1024, 256, 0, stream>>>(xe, we, eb, out, wl_count, wl);
}

// Round 13
// 278.372 us; speedup vs baseline: 1.2223x; 1.2223x over previous
//
#include <hip/hip_runtime.h>
#include <hip/hip_bf16.h>
#include <stdint.h>

typedef __attribute__((ext_vector_type(8))) short short8;
typedef __attribute__((ext_vector_type(4))) float f32x4;

#define M_ROWS 8192
#define K_DIM  4096
#define N_COLS 4096
#define NT     (K_DIM / 64)   // 64 K-tiles
#define WL_CAP (1 << 20)

// sqrt(2) in fp64: 0x3FF6A09E667F3BCD (slightly ABOVE true sqrt2).
#define SQRT2_MANT 0x6A09E667F3BCDLL
// flag margin: ~2^-11 relative; hard MFMA accumulation error bound is 2^-12
#define FLAG_MARGIN 3110000000000LL

__device__ __forceinline__ int rlog2_mask(double a) {
    if (!(a > 1e-38)) return -128;
    long long b = __double_as_longlong(a);
    int E = (int)(b >> 52) - 1023;
    long long m = b & 0xFFFFFFFFFFFFFLL;
    int e = E + (int)(m >= SQRT2_MANT);
    return e < -128 ? -128 : (e > 127 ? 127 : e);
}

__device__ __forceinline__ double pow2d(int e) {
    return __longlong_as_double((long long)(e + 1023) << 52);
}

__device__ __forceinline__ unsigned short bf16_pow2(int e) {
    if (e >= -126) return (unsigned short)((e + 127) << 7);
    int sh = 133 + e;
    return (unsigned short)(sh >= 0 ? (1 << sh) : 0);
}

__device__ __forceinline__ int bf16_exp(unsigned short u) {
    int ex = (u >> 7) & 0xFF;
    if (ex) return ex - 127;
    int m = u & 0x7F;
    return m ? (-133 + (31 - __clz(m))) : -1000;
}

__device__ __forceinline__ float finalize_out(int em, int ebj) {
    double s = pow2d(em) + pow2d(ebj);
    return (float)pow2d(rlog2_mask(s));
}

// ---------------- quantization (x and w fused in one launch) ----------------
__device__ __forceinline__ ushort4 quant4(float4 v) {
    ushort4 o;
    o.x = bf16_pow2(rlog2_mask(fabs((double)v.x)));
    o.y = bf16_pow2(rlog2_mask(fabs((double)v.y)));
    o.z = bf16_pow2(rlog2_mask(fabs((double)v.z)));
    o.w = bf16_pow2(rlog2_mask(fabs((double)v.w)));
    return o;
}

__global__ void quant_kernel(const float* __restrict__ x, const float* __restrict__ w,
                             unsigned short* __restrict__ xq, unsigned short* __restrict__ wq,
                             int nx4, int nw4) {
    int idx = blockIdx.x * blockDim.x + threadIdx.x;
    int stride = gridDim.x * blockDim.x;
    int total = nx4 + nw4;
    for (int i = idx; i < total; i += stride) {
        if (i < nx4) {
            float4 v = ((const float4*)x)[i];
            ((ushort4*)xq)[i] = quant4(v);
        } else {
            float4 v = ((const float4*)w)[i - nx4];
            ((ushort4*)wq)[i - nx4] = quant4(v);
        }
    }
}

__global__ void quant_bias_kernel(const float* __restrict__ b, int* __restrict__ eb, int n) {
    int i = blockIdx.x * blockDim.x + threadIdx.x;
    if (i < n) eb[i] = rlog2_mask(fabs((double)b[i]));
}

// ---------------- 256x256 GEMM (16x16x32 MFMA, persistent 2-tile blocks) ----------------
__device__ __forceinline__ void g2lds16(const unsigned short* g, unsigned short* l) {
    __builtin_amdgcn_global_load_lds(
        (const __attribute__((address_space(1))) unsigned int*)g,
        (__attribute__((address_space(3))) unsigned int*)l, 16, 0, 0);
}

#define LD8(p, off) (*(const short8*)((const char*)(p) + (off)))
#define MFMA16(a, b, c) __builtin_amdgcn_mfma_f32_16x16x32_bf16((a), (b), (c), 0, 0, 0)

__global__ __launch_bounds__(512, 2) void gemm_kernel(
    const unsigned short* __restrict__ xq, const unsigned short* __restrict__ wq,
    const int* __restrict__ eb, float* __restrict__ out,
    int* __restrict__ wl_count, int* __restrict__ wl)
{
    // Per 64KB buffer (shorts): A0 [0,8192) A1 [8192,16384) B0 [16384,24576) B1 [24576,32768)
    // 16KB half-tile = [2 kk][128 rows][32 cols] bf16, 64B row pitch,
    // st_16x32 swizzle: byte ^= ((byte>>9)&1)<<5.
    __shared__ unsigned short lds[2][32768];

    const int tid = threadIdx.x;
    const int lane = tid & 63, w = tid >> 6;
    const int wm = w >> 2, wn = w & 3;
    const int l15 = lane & 15, lhi = lane >> 4;

    // Persistent 2D XCD tiling: 256 blocks (1/CU), each does 2 M-tiles.
    // XCD x owns bm [(x&3)*8,+8) x bn [(x>>2)*8,+8); per residency round the
    // XCD touches 4 A-panels + 8 B-panels = 24 MB (R10-proven locality).
    const int x = blockIdx.x & 7;
    const int j = blockIdx.x >> 3;          // 0..31
    const int bm0 = (x & 3) * 8 + (j & 3);  // tile 1; tile 2 = bm0 + 4
    const int bn  = (x >> 2) * 8 + (j >> 2);
    const int bcol = bn * 256;

    // staging thread->coord (pre-swizzled global, linear LDS dest)
    int p0 = tid * 16;
    int lin0 = p0 ^ (((p0 >> 9) & 1) << 5);
    int row0 = (lin0 >> 6) & 127;
    int col0 = (((lin0 >> 13) << 6) | (lin0 & 63)) >> 1;
    int p1 = 8192 + tid * 16;
    int lin1 = p1 ^ (((p1 >> 9) & 1) << 5);
    int row1 = (lin1 >> 6) & 127;
    int col1 = (((lin1 >> 13) << 6) | (lin1 & 63)) >> 1;

    // fragment read base (bytes, swizzled)
    int fsw = l15 * 64 + lhi * 16;
    fsw ^= ((l15 >> 3) & 1) << 5;

    const char* pA_0 = (const char*)&lds[0][wm * 8192] + fsw;
    const char* pA_1 = (const char*)&lds[1][wm * 8192] + fsw;
    const char* pB_0 = (const char*)&lds[0][16384 + (wn >> 1) * 8192 + (wn & 1) * 2048] + fsw;
    const char* pB_1 = (const char*)&lds[1][16384 + (wn >> 1) * 8192 + (wn & 1) * 2048] + fsw;

#define STAGE_A(b, h, OFFE) do { \
        g2lds16(((h) ? aS0h1 : aS0h0) + (OFFE), &lds[b][(h) * 8192] + wofs); \
        g2lds16(((h) ? aS1h1 : aS1h0) + (OFFE), &lds[b][(h) * 8192 + 4096] + wofs); \
    } while (0)
#define STAGE_B(b, h, OFFE) do { \
        g2lds16(((h) ? bS0h1 : bS0h0) + (OFFE), &lds[b][16384 + (h) * 8192] + wofs); \
        g2lds16(((h) ? bS1h1 : bS1h0) + (OFFE), &lds[b][16384 + (h) * 8192 + 4096] + wofs); \
    } while (0)
#define DS_A4(P, mb) do { \
        aF[0][0] = LD8(P, ((mb) + 0) * 1024); aF[0][1] = LD8(P, ((mb) + 0) * 1024 + 8192); \
        aF[1][0] = LD8(P, ((mb) + 1) * 1024); aF[1][1] = LD8(P, ((mb) + 1) * 1024 + 8192); \
        aF[2][0] = LD8(P, ((mb) + 2) * 1024); aF[2][1] = LD8(P, ((mb) + 2) * 1024 + 8192); \
        aF[3][0] = LD8(P, ((mb) + 3) * 1024); aF[3][1] = LD8(P, ((mb) + 3) * 1024 + 8192); \
    } while (0)
#define DS_B2(P, arr, cb) do { \
        arr[0][0] = LD8(P, ((cb) + 0) * 1024); arr[0][1] = LD8(P, ((cb) + 0) * 1024 + 8192); \
        arr[1][0] = LD8(P, ((cb) + 1) * 1024); arr[1][1] = LD8(P, ((cb) + 1) * 1024 + 8192); \
    } while (0)
#define MFMA_Q(mb, nb, B) do { \
        _Pragma("unroll") \
        for (int m_ = 0; m_ < 4; ++m_) \
        _Pragma("unroll") \
        for (int n_ = 0; n_ < 2; ++n_) { \
            acc[(mb) + m_][(nb) + n_] = MFMA16(aF[m_][0], B[n_][0], acc[(mb) + m_][(nb) + n_]); \
            acc[(mb) + m_][(nb) + n_] = MFMA16(aF[m_][1], B[n_][1], acc[(mb) + m_][(nb) + n_]); \
        } \
    } while (0)

#define BAR()  __builtin_amdgcn_s_barrier()
#define PRIO1() __builtin_amdgcn_s_setprio(1)
#define PRIO0() __builtin_amdgcn_s_setprio(0)

    const int wofs = w * 512;

    for (int ht = 0; ht < 2; ++ht) {
        const int bm = bm0 + ht * 4;
        const int brow = bm * 256;

        // 8 rolling global pointers (advance +128 elems / iteration = 2 K-tiles)
        const unsigned short* aS0h0 = xq + (size_t)(brow + row0) * K_DIM + col0;
        const unsigned short* aS1h0 = xq + (size_t)(brow + row1) * K_DIM + col1;
        const unsigned short* aS0h1 = aS0h0 + (size_t)128 * K_DIM;
        const unsigned short* aS1h1 = aS1h0 + (size_t)128 * K_DIM;
        const unsigned short* bS0h0 = wq + (size_t)(bcol + row0) * K_DIM + col0;
        const unsigned short* bS1h0 = wq + (size_t)(bcol + row1) * K_DIM + col1;
        const unsigned short* bS0h1 = bS0h0 + (size_t)128 * K_DIM;
        const unsigned short* bS1h1 = bS1h0 + (size_t)128 * K_DIM;

        f32x4 acc[8][4];
#pragma unroll
        for (int m = 0; m < 8; ++m)
#pragma unroll
            for (int n = 0; n < 4; ++n) acc[m][n] = (f32x4){0.f, 0.f, 0.f, 0.f};

        short8 aF[4][2], b01[2][2], b23[2][2];

        // ---- prologue: tile0 -> buf0 (A0,A1,B0,B1), tile1 -> buf1 (B0,B1) ----
        STAGE_A(0, 0, 0);
        STAGE_A(0, 1, 0);
        STAGE_B(0, 0, 0);
        STAGE_B(0, 1, 0);
        STAGE_B(1, 0, 64);
        STAGE_B(1, 1, 64);
        asm volatile("s_waitcnt vmcnt(4)" ::: "memory");
        BAR();

        // ---- main loop: 2 K-tiles (2tt -> buf0, 2tt+1 -> buf1), 4 mega-phases ----
        for (int tt = 0; tt < NT / 2 - 1; ++tt) {
            // P1: tile t (buf0) m0-3 x all n; stage buf1.A (t+1)
            DS_B2(pB_0, b01, 0); DS_B2(pB_0, b23, 2);
            DS_A4(pA_0, 0);
            STAGE_A(1, 0, 64); STAGE_A(1, 1, 64);
            PRIO1(); MFMA_Q(0, 0, b01); MFMA_Q(0, 2, b23); PRIO0(); BAR();
            // P2: tile t m4-7; stage buf0.B (t+2); vmcnt(4) -> buf1 (t+1) complete
            DS_A4(pA_0, 4);
            STAGE_B(0, 0, 128); STAGE_B(0, 1, 128);
            PRIO1(); MFMA_Q(4, 2, b23); MFMA_Q(4, 0, b01); PRIO0();
            asm volatile("s_waitcnt vmcnt(4)" ::: "memory");
            BAR();
            // P3: tile t+1 (buf1) m0-3; stage buf0.A (t+2)
            DS_B2(pB_1, b01, 0); DS_B2(pB_1, b23, 2);
            DS_A4(pA_1, 0);
            STAGE_A(0, 0, 128); STAGE_A(0, 1, 128);
            PRIO1(); MFMA_Q(0, 0, b01); MFMA_Q(0, 2, b23); PRIO0(); BAR();
            // P4: tile t+1 m4-7; stage buf1.B (t+3); vmcnt(4) -> buf0 (t+2) complete
            DS_A4(pA_1, 4);
            STAGE_B(1, 0, 192); STAGE_B(1, 1, 192);
            PRIO1(); MFMA_Q(4, 2, b23); MFMA_Q(4, 0, b01); PRIO0();
            asm volatile("s_waitcnt vmcnt(4)" ::: "memory");
            BAR();

            aS0h0 += 128; aS1h0 += 128; aS0h1 += 128; aS1h1 += 128;
            bS0h0 += 128; bS1h0 += 128; bS0h1 += 128; bS1h1 += 128;
        }

        // ---- peeled final pair (tiles NT-2 -> buf0, NT-1 -> buf1) ----
        DS_B2(pB_0, b01, 0); DS_B2(pB_0, b23, 2);
        DS_A4(pA_0, 0);
        STAGE_A(1, 0, 64); STAGE_A(1, 1, 64);
        PRIO1(); MFMA_Q(0, 0, b01); MFMA_Q(0, 2, b23); PRIO0(); BAR();
        DS_A4(pA_0, 4);
        PRIO1(); MFMA_Q(4, 2, b23); MFMA_Q(4, 0, b01); PRIO0();
        asm volatile("s_waitcnt vmcnt(0)" ::: "memory");
        BAR();
        DS_B2(pB_1, b01, 0); DS_B2(pB_1, b23, 2);
        DS_A4(pA_1, 0);
        PRIO1(); MFMA_Q(0, 0, b01); MFMA_Q(0, 2, b23); PRIO0(); BAR();
        DS_A4(pA_1, 4);
        PRIO1(); MFMA_Q(4, 2, b23); MFMA_Q(4, 0, b01); PRIO0();

        // all waves' LDS reads must retire before next half re-stages the buffers
        BAR();

        // ---- epilogue: exponent decision + flag + finalize ----
#pragma unroll
        for (int m = 0; m < 8; ++m) {
            int grow_base = brow + wm * 128 + m * 16 + lhi * 4;
#pragma unroll
            for (int n = 0; n < 4; ++n) {
                int gcol = bcol + wn * 64 + n * 16 + l15;
                int ebj = eb[gcol];
#pragma unroll
                for (int q = 0; q < 4; ++q) {
                    float S = acc[m][n][q];
                    int grow = grow_base + q;
                    double v = (double)S;
                    int em; bool flag;
                    if (v > 1e-38) {
                        long long bb = __double_as_longlong(v);
                        long long mm = bb & 0xFFFFFFFFFFFFFLL;
                        long long d = mm - SQRT2_MANT;
                        flag = (d < 0 ? -d : d) < FLAG_MARGIN;
                        int e = ((int)(bb >> 52) - 1023) + (int)(mm >= SQRT2_MANT);
                        em = e < -128 ? -128 : (e > 127 ? 127 : e);
                    } else { em = -128; flag = true; }
                    out[(size_t)grow * N_COLS + gcol] = finalize_out(em, ebj);
                    if (flag) {
                        int pos = atomicAdd(wl_count, 1);
                        if (pos < WL_CAP) wl[pos] = grow * N_COLS + gcol;
                    }
                }
            }
        }
    }
}

// ---------------- exact fixup for flagged outputs ----------------
__global__ __launch_bounds__(256) void fixup_kernel(
    const unsigned short* __restrict__ xq, const unsigned short* __restrict__ wq,
    const int* __restrict__ eb, float* __restrict__ out,
    const int* __restrict__ wl_count, const int* __restrict__ wl)
{
    const int nwaves = (gridDim.x * blockDim.x) >> 6;
    const int gw = (blockIdx.x * blockDim.x + threadIdx.x) >> 6;
    const int lane = threadIdx.x & 63;
    int count = *wl_count;
    if (count > WL_CAP) count = WL_CAP;
    for (int it = gw; it < count; it += nwaves) {
        int lin = wl[it];
        int i = lin >> 12;
        int j = lin & 4095;
        const unsigned short* xr = xq + (size_t)i * K_DIM;
        const unsigned short* wr = wq + (size_t)j * K_DIM;
        unsigned long long accu = 0;
        for (int kb = 0; kb < K_DIM / 256; ++kb) {
            int k0 = kb * 256 + lane * 4;
            ushort4 xv = *(const ushort4*)(xr + k0);
            ushort4 wv = *(const ushort4*)(wr + k0);
            int p;
            p = bf16_exp(xv.x) + bf16_exp(wv.x) + 56; if ((unsigned)p <= 62u) accu += 1ULL << p;
            p = bf16_exp(xv.y) + bf16_exp(wv.y) + 56; if ((unsigned)p <= 62u) accu += 1ULL << p;
            p = bf16_exp(xv.z) + bf16_exp(wv.z) + 56; if ((unsigned)p <= 62u) accu += 1ULL << p;
            p = bf16_exp(xv.w) + bf16_exp(wv.w) + 56; if ((unsigned)p <= 62u) accu += 1ULL << p;
        }
#pragma unroll
        for (int off = 32; off; off >>= 1) accu += __shfl_down(accu, off, 64);
        if (lane == 0) {
            double S = (double)accu * 0x1p-56;
            int em = rlog2_mask(S);
            out[lin] = finalize_out(em, eb[j]);
        }
    }
}

extern "C" void kernel_launch(void* const* d_in, const int* in_sizes, int n_in,
                              void* d_out, int out_size, void* d_ws, size_t ws_size,
                              hipStream_t stream) {
    const float* x    = (const float*)d_in[0];
    const float* w    = (const float*)d_in[1];
    const float* bias = (const float*)d_in[2];
    float* out = (float*)d_out;
    char* ws = (char*)d_ws;

    int* wl_count = (int*)ws;
    int* eb       = (int*)(ws + 256);
    unsigned short* xq = (unsigned short*)(ws + 32768);
    unsigned short* wq = (unsigned short*)(ws + 32768 + (size_t)M_ROWS * K_DIM * 2);
    int* wl = (int*)(ws + 32768 + (size_t)M_ROWS * K_DIM * 2 + (size_t)N_COLS * K_DIM * 2);

    hipMemsetAsync(wl_count, 0, 4, stream);
    quant_kernel<<<3072, 256, 0, stream>>>(x, w, xq, wq,
                                           M_ROWS * K_DIM / 4, N_COLS * K_DIM / 4);
    quant_bias_kernel<<<16, 256, 0, stream>>>(bias, eb, N_COLS);
    gemm_kernel<<<dim3(256), 512, 0, stream>>>(xq, wq, eb, out, wl_count, wl);
    fixup_kernel<<<1024, 256, 0, stream>>>(xq, wq, eb, out, wl_count, wl);
}